// Round 7
// baseline (215.355 us; speedup 1.0000x reference)
//
#include <hip/hip_runtime.h>
#include <stdint.h>

#define DMODEL 768
#define NHEADS 12
#define DK 64
#define BATCH 4
#define SEQ 2048
#define MTOK (BATCH*SEQ)   // 8192 tokens

typedef float f32x4 __attribute__((ext_vector_type(4)));
typedef float f32x16 __attribute__((ext_vector_type(16)));
typedef short bf16x8 __attribute__((ext_vector_type(8)));
typedef unsigned short u16;
typedef unsigned int u32;

#define LOG2E 1.4426950408889634f

__device__ __forceinline__ u16 f2bf(float f) {
  uint32_t u = __float_as_uint(f);
  u += 0x7FFFu + ((u >> 16) & 1u);   // RNE
  return (u16)(u >> 16);
}

// async global->LDS, 16B per lane; LDS dest is wave-uniform base + lane*16
#define GLDS16(g, l) __builtin_amdgcn_global_load_lds( \
    (const __attribute__((address_space(1))) unsigned int*)(g), \
    (__attribute__((address_space(3))) unsigned int*)(l), 16, 0, 0)

// ---------------- fused fp32 -> bf16 convert (x + 4 weights, one launch) ----------------
__global__ void cvt_all(const float* __restrict__ x,
                        const float* __restrict__ wq, const float* __restrict__ wk,
                        const float* __restrict__ wv, const float* __restrict__ wo,
                        u16* __restrict__ xb, u16* __restrict__ wb) {
  const int NX = MTOK * DMODEL / 4;     // 1,572,864
  const int NW = DMODEL * DMODEL / 4;   // 147,456
  int i = blockIdx.x * blockDim.x + threadIdx.x;
  const float* src; u16* dst; int idx;
  if (i < NX) {
    src = x; dst = xb; idx = i;
  } else {
    const int j = i - NX;
    const int w = j / NW;               // 0..3 (constant divisor -> magic mul)
    idx = j - w * NW;
    src = (w == 0) ? wq : (w == 1) ? wk : (w == 2) ? wv : wo;
    dst = wb + (size_t)w * DMODEL * DMODEL;
  }
  float4 v = reinterpret_cast<const float4*>(src)[idx];
  ushort4 o;
  o.x = f2bf(v.x); o.y = f2bf(v.y); o.z = f2bf(v.z); o.w = f2bf(v.w);
  reinterpret_cast<ushort4*>(dst)[idx] = o;
}

// ---------------- GEMM main loop: 128x128 tile, m97 4-wave shape ----------------
#define BM 128
#define BN 128
#define BK 32

__device__ __forceinline__ void gemm_loop(const u16* __restrict__ A, const u16* __restrict__ W,
                                          int bm, int bn, int t, u16* As, u16* Ws,
                                          f32x4 (&acc)[4][4]) {
  const int lane = t & 63;
  const int wave = t >> 6;              // 0..3
  const int r16 = lane & 15, g = lane >> 4;
  const int wr = (wave >> 1) * 64;
  const int wc = (wave & 1) * 64;
  // 512 chunks of 16B per matrix; thread t handles chunks {t, t+256}
  // chunk c: row = c>>2, LDS slot = c*16B, source col-chunk = (c&3)^((c>>3)&3)
  const int c0 = t, c1 = t + 256;
  const int r0 = c0 >> 2, k0 = ((c0 & 3) ^ ((c0 >> 3) & 3)) * 8;
  const int r1 = c1 >> 2, k1 = ((c1 & 3) ^ ((c1 >> 3) & 3)) * 8;
  const size_t a0 = (size_t)(bm + r0) * DMODEL + k0;
  const size_t a1 = (size_t)(bm + r1) * DMODEL + k1;
  const size_t w0 = (size_t)(bn + r0) * DMODEL + k0;
  const size_t w1 = (size_t)(bn + r1) * DMODEL + k1;

  GLDS16(A + a0, As + c0 * 8); GLDS16(A + a1, As + c1 * 8);
  GLDS16(W + w0, Ws + c0 * 8); GLDS16(W + w1, Ws + c1 * 8);
  __syncthreads();

  const int NK = DMODEL / BK;   // 24
  for (int kt = 0; kt < NK; ++kt) {
    const int cur = kt & 1;
    if (kt + 1 < NK) {
      const size_t koff = (size_t)(kt + 1) * BK;
      GLDS16(A + a0 + koff, As + (cur ^ 1) * 4096 + c0 * 8);
      GLDS16(A + a1 + koff, As + (cur ^ 1) * 4096 + c1 * 8);
      GLDS16(W + w0 + koff, Ws + (cur ^ 1) * 4096 + c0 * 8);
      GLDS16(W + w1 + koff, Ws + (cur ^ 1) * 4096 + c1 * 8);
    }
    bf16x8 af[4], bfr[4];
#pragma unroll
    for (int m = 0; m < 4; ++m) {
      const int row = wr + m * 16 + r16;
      af[m] = *reinterpret_cast<const bf16x8*>(&As[cur * 4096 + row * 32 + ((g ^ ((row >> 1) & 3)) * 8)]);
    }
#pragma unroll
    for (int n = 0; n < 4; ++n) {
      const int row = wc + n * 16 + r16;
      bfr[n] = *reinterpret_cast<const bf16x8*>(&Ws[cur * 4096 + row * 32 + ((g ^ ((row >> 1) & 3)) * 8)]);
    }
#pragma unroll
    for (int m = 0; m < 4; ++m)
#pragma unroll
      for (int n = 0; n < 4; ++n)
        acc[m][n] = __builtin_amdgcn_mfma_f32_16x16x32_bf16(af[m], bfr[n], acc[m][n], 0, 0, 0);
    __syncthreads();
  }
}

// Fused QKV projection: z=0 Q (pre-scaled by 0.125*log2e), z=1 K, z=2 V^T
__launch_bounds__(256)
__global__ void qkv_gemm(const u16* __restrict__ A, const u16* __restrict__ wAll,
                         u16* __restrict__ Qw, u16* __restrict__ Kw, u16* __restrict__ Vtw) {
  __shared__ __align__(16) u16 As[2 * BM * BK];
  __shared__ __align__(16) u16 Ws[2 * BN * BK];
  const int t = threadIdx.x;
  const int lane = t & 63, wave = t >> 6;
  const int r16 = lane & 15, g = lane >> 4;
  const int bm = blockIdx.x * BM, bn = blockIdx.y * BN;
  const int z = blockIdx.z;
  const u16* W = wAll + (size_t)z * DMODEL * DMODEL;
  const int wr = (wave >> 1) * 64, wc = (wave & 1) * 64;

  f32x4 acc[4][4] = {};
  gemm_loop(A, W, bm, bn, t, As, Ws, acc);

  if (z <= 1) {
    u16* Qo = (z == 0) ? Qw : Kw;
    const float scl = (z == 0) ? (0.125f * LOG2E) : 1.0f;  // base-2 softmax domain
#pragma unroll
    for (int m = 0; m < 4; ++m) {
      const int gi0 = bm + wr + m * 16 + g * 4;
#pragma unroll
      for (int n = 0; n < 4; ++n) {
        const int gj = bn + wc + n * 16 + r16;
        const int h = gj >> 6, dc = gj & 63;
#pragma unroll
        for (int r = 0; r < 4; ++r) {
          const int gi = gi0 + r;
          const int b_ = gi >> 11, s = gi & 2047;
          Qo[((size_t)((b_ * NHEADS + h) * SEQ + s) << 6) + dc] = f2bf(acc[m][n][r] * scl);
        }
      }
    }
  } else {
    // V^T: Vo[b][h][dc][s], 4 consecutive s per lane -> packed ushort4 store
#pragma unroll
    for (int m = 0; m < 4; ++m) {
      const int gi0 = bm + wr + m * 16 + g * 4;
      const int b_ = gi0 >> 11, s0 = gi0 & 2047;
#pragma unroll
      for (int n = 0; n < 4; ++n) {
        const int gj = bn + wc + n * 16 + r16;
        const int h = gj >> 6, dc = gj & 63;
        ushort4 pk;
        pk.x = f2bf(acc[m][n][0]); pk.y = f2bf(acc[m][n][1]);
        pk.z = f2bf(acc[m][n][2]); pk.w = f2bf(acc[m][n][3]);
        *reinterpret_cast<ushort4*>(Vtw + ((size_t)((b_ * NHEADS + h) * DK + dc) * SEQ + s0)) = pk;
      }
    }
  }
}

// Output projection: BM=64 x BN=128 tiles (grid 768 = 3 blocks/CU), fp32 out [M][N]
__launch_bounds__(256)
__global__ void out_gemm(const u16* __restrict__ A, const u16* __restrict__ W,
                         float* __restrict__ C) {
  __shared__ __align__(16) u16 As[2 * 64 * BK];    // 8 KB
  __shared__ __align__(16) u16 Ws[2 * BN * BK];    // 16 KB
  const int t = threadIdx.x;
  const int lane = t & 63, wave = t >> 6;
  const int r16 = lane & 15, g = lane >> 4;
  const int bm = blockIdx.x * 64, bn = blockIdx.y * BN;
  const int wr = (wave >> 1) * 32, wc = (wave & 1) * 64;

  // A-tile: 256 chunks (1/thread); W-tile: 512 chunks (2/thread)
  const int ca = t, ra = ca >> 2, ka = ((ca & 3) ^ ((ca >> 3) & 3)) * 8;
  const int c1 = t + 256, r1 = c1 >> 2, k1 = ((c1 & 3) ^ ((c1 >> 3) & 3)) * 8;
  const size_t aoff = (size_t)(bm + ra) * DMODEL + ka;
  const size_t w0 = (size_t)(bn + ra) * DMODEL + ka;
  const size_t w1 = (size_t)(bn + r1) * DMODEL + k1;

  f32x4 acc[2][4] = {};

  GLDS16(A + aoff, As + ca * 8);
  GLDS16(W + w0, Ws + ca * 8); GLDS16(W + w1, Ws + c1 * 8);
  __syncthreads();

  const int NK = DMODEL / BK;   // 24
  for (int kt = 0; kt < NK; ++kt) {
    const int cur = kt & 1;
    if (kt + 1 < NK) {
      const size_t koff = (size_t)(kt + 1) * BK;
      GLDS16(A + aoff + koff, As + (cur ^ 1) * 2048 + ca * 8);
      GLDS16(W + w0 + koff, Ws + (cur ^ 1) * 4096 + ca * 8);
      GLDS16(W + w1 + koff, Ws + (cur ^ 1) * 4096 + c1 * 8);
    }
    bf16x8 af[2], bfr[4];
#pragma unroll
    for (int m = 0; m < 2; ++m) {
      const int row = wr + m * 16 + r16;
      af[m] = *reinterpret_cast<const bf16x8*>(&As[cur * 2048 + row * 32 + ((g ^ ((row >> 1) & 3)) * 8)]);
    }
#pragma unroll
    for (int n = 0; n < 4; ++n) {
      const int row = wc + n * 16 + r16;
      bfr[n] = *reinterpret_cast<const bf16x8*>(&Ws[cur * 4096 + row * 32 + ((g ^ ((row >> 1) & 3)) * 8)]);
    }
#pragma unroll
    for (int m = 0; m < 2; ++m)
#pragma unroll
      for (int n = 0; n < 4; ++n)
        acc[m][n] = __builtin_amdgcn_mfma_f32_16x16x32_bf16(af[m], bfr[n], acc[m][n], 0, 0, 0);
    __syncthreads();
  }

#pragma unroll
  for (int m = 0; m < 2; ++m) {
    const int gi0 = bm + wr + m * 16 + g * 4;
#pragma unroll
    for (int n = 0; n < 4; ++n) {
      const int gj = bn + wc + n * 16 + r16;
#pragma unroll
      for (int r = 0; r < 4; ++r)
        C[(size_t)(gi0 + r) * DMODEL + gj] = acc[m][n][r];
    }
  }
}

// ---- P fragment assembly: 8 own f32 P-values -> bf16x8 PV B-operand frag ----
__device__ __forceinline__ bf16x8 mk_pa(int hi, float p0, float p1, float p2, float p3,
                                        float p4, float p5, float p6, float p7) {
  u32 w01, w23, w45, w67;
  asm("v_cvt_pk_bf16_f32 %0, %1, %2" : "=v"(w01) : "v"(p0), "v"(p1));
  asm("v_cvt_pk_bf16_f32 %0, %1, %2" : "=v"(w23) : "v"(p2), "v"(p3));
  asm("v_cvt_pk_bf16_f32 %0, %1, %2" : "=v"(w45) : "v"(p4), "v"(p5));
  asm("v_cvt_pk_bf16_f32 %0, %1, %2" : "=v"(w67) : "v"(p6), "v"(p7));
  const u32 pw01 = (u32)__shfl_xor((int)w01, 32);
  const u32 pw23 = (u32)__shfl_xor((int)w23, 32);
  const u32 pw45 = (u32)__shfl_xor((int)w45, 32);
  const u32 pw67 = (u32)__shfl_xor((int)w67, 32);
  union { u32 w[4]; bf16x8 v; } u;
  u.w[0] = hi ? pw45 : w01;
  u.w[1] = hi ? pw67 : w23;
  u.w[2] = hi ? w45  : pw01;
  u.w[3] = hi ? w67  : pw23;
  return u.v;
}

// ---------------- causal flash attention: 64-row q-tiles, 2-warp blocks ----------------
// grid 1536 LPT-ordered; 5 blocks/CU resident (32KB LDS) + 256 queued -> backfill
// smooths the causal tail. Same verified swapped-QK 32x32 compute body.
__launch_bounds__(128)
__global__ void attn_kernel(const u16* __restrict__ Qg, const u16* __restrict__ Kg,
                            const u16* __restrict__ Vtg, u16* __restrict__ Og) {
  __shared__ __align__(16) u16 Ks[2][64 * 64];
  __shared__ __align__(16) u16 Vs[2][64 * 64];
  const int t = threadIdx.x;            // 0..127
  const int lane = t & 63, warp = t >> 6;   // warp 0..1
  const int l31 = lane & 31, hi = lane >> 5;
  const int bx = blockIdx.x;            // 0..1535
  const int qt = 31 - (bx / 48);        // LPT: heaviest q-tiles dispatched first
  const int hb = bx % 48;
  const int h = hb % NHEADS, b = hb / NHEADS;
  const int q0w = qt * 64 + warp * 32;
  const int nt = qt + 1;                // kv tiles (of 64) this block needs
  const size_t bh = (size_t)(b * NHEADS + h);
  const u16* Qb = Qg + bh * SEQ * DK;
  const u16* Kb = Kg + bh * SEQ * DK;
  const u16* Vb = Vtg + bh * DK * SEQ;  // [d][s]

  // staging map: 512 chunks of 16B per tile, 4 per thread
  int srow[4], scol[4];
#pragma unroll
  for (int j = 0; j < 4; ++j) {
    const int bb = (t + j * 128) * 16;
    srow[j] = bb >> 7;
    scol[j] = ((bb & 127) ^ ((srow[j] & 7) << 4)) >> 1;
  }

  const int q = q0w + l31;              // this lane's q-row
  bf16x8 qf[4];                         // Q pre-scaled by 0.125*log2e in projection
#pragma unroll
  for (int kk = 0; kk < 4; ++kk)
    qf[kk] = *reinterpret_cast<const bf16x8*>(Qb + (size_t)q * DK + kk * 16 + hi * 8);

  f32x16 o0 = {}, o1 = {};              // O^T: d = crow(reg,hi) + 32*{0,1}
  float m = -__builtin_inff(), l = 0.f;
  const int hi4 = hi * 4;
  const int xr = (l31 & 7) << 4;

  // prologue: stage tile 0 into buffer 0
#pragma unroll
  for (int j = 0; j < 4; ++j) {
    GLDS16(Kb + (size_t)srow[j] * DK + scol[j], &Ks[0][0] + (t + j * 128) * 8);
    GLDS16(Vb + (size_t)srow[j] * SEQ + scol[j], &Vs[0][0] + (t + j * 128) * 8);
  }
  __syncthreads();

  for (int i = 0; i < nt; ++i) {
    const int cur = i & 1;
    const int kv0 = i * 64;
    if (i + 1 < nt) {                   // issue next tile early
      const int nkv0 = kv0 + 64;
#pragma unroll
      for (int j = 0; j < 4; ++j) {
        GLDS16(Kb + (size_t)(nkv0 + srow[j]) * DK + scol[j], &Ks[cur ^ 1][0] + (t + j * 128) * 8);
        GLDS16(Vb + (size_t)srow[j] * SEQ + nkv0 + scol[j], &Vs[cur ^ 1][0] + (t + j * 128) * 8);
      }
    }

    {
      // ---- T = K Q^T (scores already in base-2 domain) ----
      f32x16 t0 = {}, t1 = {};
      const char* Kc = (const char*)Ks[cur];
      __builtin_amdgcn_s_setprio(1);
#pragma unroll
      for (int kk = 0; kk < 4; ++kk) {
        const int cb = kk * 32 + hi * 16;
        bf16x8 a0 = *reinterpret_cast<const bf16x8*>(Kc + ((l31 * 128 + cb) ^ xr));
        bf16x8 a1 = *reinterpret_cast<const bf16x8*>(Kc + (((l31 + 32) * 128 + cb) ^ xr));
        t0 = __builtin_amdgcn_mfma_f32_32x32x16_bf16(a0, qf[kk], t0, 0, 0, 0);
        t1 = __builtin_amdgcn_mfma_f32_32x32x16_bf16(a1, qf[kk], t1, 0, 0, 0);
      }
      __builtin_amdgcn_s_setprio(0);

      // ---- causal mask (diag tile only) ----
      if (kv0 + 63 > q0w) {
        const int qmh = (q - kv0) - hi4;
#pragma unroll
        for (int r = 0; r < 16; ++r) {
          const int kvc = (r & 3) + 8 * (r >> 2);
          if (kvc > qmh)      t0[r] = -__builtin_inff();
          if (kvc + 32 > qmh) t1[r] = -__builtin_inff();
        }
      }

      // ---- row max ----
      float x0 = fmaxf(t0[0], t0[1]),  x1 = fmaxf(t0[2], t0[3]);
      float x2 = fmaxf(t0[4], t0[5]),  x3 = fmaxf(t0[6], t0[7]);
      float x4 = fmaxf(t0[8], t0[9]),  x5 = fmaxf(t0[10], t0[11]);
      float x6 = fmaxf(t0[12], t0[13]), x7 = fmaxf(t0[14], t0[15]);
      x0 = fmaxf(x0, x1); x2 = fmaxf(x2, x3); x4 = fmaxf(x4, x5); x6 = fmaxf(x6, x7);
      float y0 = fmaxf(t1[0], t1[1]),  y1 = fmaxf(t1[2], t1[3]);
      float y2 = fmaxf(t1[4], t1[5]),  y3 = fmaxf(t1[6], t1[7]);
      float y4 = fmaxf(t1[8], t1[9]),  y5 = fmaxf(t1[10], t1[11]);
      float y6 = fmaxf(t1[12], t1[13]), y7 = fmaxf(t1[14], t1[15]);
      y0 = fmaxf(y0, y1); y2 = fmaxf(y2, y3); y4 = fmaxf(y4, y5); y6 = fmaxf(y6, y7);
      float pm = fmaxf(fmaxf(fmaxf(x0, x2), fmaxf(x4, x6)),
                       fmaxf(fmaxf(y0, y2), fmaxf(y4, y6)));
      pm = fmaxf(pm, __shfl_xor(pm, 32));

      if (pm > m) {                     // exact skip-rescale
        const float corr = __builtin_amdgcn_exp2f(m - pm);
        l *= corr;
        o0 = o0 * corr;
        o1 = o1 * corr;
        m = pm;
      }

      // ---- exp2 + row sum ----
#pragma unroll
      for (int r = 0; r < 16; ++r) { t0[r] = __builtin_amdgcn_exp2f(t0[r] - m); }
#pragma unroll
      for (int r = 0; r < 16; ++r) { t1[r] = __builtin_amdgcn_exp2f(t1[r] - m); }
      float s0 = 0.f, s1 = 0.f, s2 = 0.f, s3 = 0.f;
#pragma unroll
      for (int r = 0; r < 4; ++r) {
        s0 += t0[r]; s1 += t0[4 + r]; s2 += t0[8 + r]; s3 += t0[12 + r];
        s0 += t1[r]; s1 += t1[4 + r]; s2 += t1[8 + r]; s3 += t1[12 + r];
      }
      float s = (s0 + s1) + (s2 + s3);
      l += s + __shfl_xor(s, 32);

      // ---- P -> bf16 PV fragments (in-register) ----
      bf16x8 pa0 = mk_pa(hi, t0[0], t0[1], t0[2], t0[3], t0[4], t0[5], t0[6], t0[7]);
      bf16x8 pa1 = mk_pa(hi, t0[8], t0[9], t0[10], t0[11], t0[12], t0[13], t0[14], t0[15]);
      bf16x8 pa2 = mk_pa(hi, t1[0], t1[1], t1[2], t1[3], t1[4], t1[5], t1[6], t1[7]);
      bf16x8 pa3 = mk_pa(hi, t1[8], t1[9], t1[10], t1[11], t1[12], t1[13], t1[14], t1[15]);

      // ---- O^T += V^T P^T ----
      const char* Vc = (const char*)Vs[cur];
      __builtin_amdgcn_s_setprio(1);
#pragma unroll
      for (int ks = 0; ks < 4; ++ks) {
        const int cb = ks * 32 + hi * 16;
        bf16x8 v0 = *reinterpret_cast<const bf16x8*>(Vc + ((l31 * 128 + cb) ^ xr));
        bf16x8 v1 = *reinterpret_cast<const bf16x8*>(Vc + (((l31 + 32) * 128 + cb) ^ xr));
        const bf16x8 pk = (ks == 0) ? pa0 : (ks == 1) ? pa1 : (ks == 2) ? pa2 : pa3;
        o0 = __builtin_amdgcn_mfma_f32_32x32x16_bf16(v0, pk, o0, 0, 0, 0);
        o1 = __builtin_amdgcn_mfma_f32_32x32x16_bf16(v1, pk, o1, 0, 0, 0);
      }
      __builtin_amdgcn_s_setprio(0);
    }
    __syncthreads();                    // drains GLDS (vmcnt) + publishes buf^1
  }

  // ---- epilogue: O^T/l -> Og[tok][DMODEL] ----
  const float rinv = 1.0f / l;
  u16* orow = Og + (size_t)(b * SEQ + q) * DMODEL + h * 64;
#pragma unroll
  for (int j = 0; j < 4; ++j) {
    ushort4 pk;
    pk.x = f2bf(o0[4 * j + 0] * rinv); pk.y = f2bf(o0[4 * j + 1] * rinv);
    pk.z = f2bf(o0[4 * j + 2] * rinv); pk.w = f2bf(o0[4 * j + 3] * rinv);
    *reinterpret_cast<ushort4*>(orow + 8 * j + hi4) = pk;
  }
#pragma unroll
  for (int j = 0; j < 4; ++j) {
    ushort4 pk;
    pk.x = f2bf(o1[4 * j + 0] * rinv); pk.y = f2bf(o1[4 * j + 1] * rinv);
    pk.z = f2bf(o1[4 * j + 2] * rinv); pk.w = f2bf(o1[4 * j + 3] * rinv);
    *reinterpret_cast<ushort4*>(orow + 32 + 8 * j + hi4) = pk;
  }
}

// ---------------- launch ----------------
extern "C" void kernel_launch(void* const* d_in, const int* in_sizes, int n_in,
                              void* d_out, int out_size, void* d_ws, size_t ws_size,
                              hipStream_t stream) {
  const float* x  = (const float*)d_in[0];
  const float* wq = (const float*)d_in[1];
  const float* wk = (const float*)d_in[2];
  const float* wv = (const float*)d_in[3];
  const float* wo = (const float*)d_in[4];

  const size_t SZ_TOK = (size_t)MTOK * DMODEL * 2;
  const size_t SZ_W   = (size_t)DMODEL * DMODEL * 2;
  char* ws = (char*)d_ws;
  size_t off = 0;
  u16* xb  = (u16*)(ws + off); off += SZ_TOK;
  u16* wqb = (u16*)(ws + off); off += 4 * SZ_W;   // wq,wk,wv,wo contiguous
  u16* Qw  = (u16*)(ws + off); off += SZ_TOK;
  u16* Kw  = (u16*)(ws + off); off += SZ_TOK;
  u16* Vtw = (u16*)(ws + off); off += SZ_TOK;     // [B,H,DK,S]
  u16* Ow  = (u16*)(ws + off); off += SZ_TOK;
  if (ws_size < off) return;
  u16* wob = wqb + 3 * (size_t)DMODEL * DMODEL;

  const int NX = MTOK * DMODEL / 4;
  const int NW = DMODEL * DMODEL / 4;
  cvt_all<<<(NX + 4 * NW) / 256, 256, 0, stream>>>(x, wq, wk, wv, wo, xb, wqb);

  qkv_gemm<<<dim3(MTOK / BM, DMODEL / BN, 3), 256, 0, stream>>>(xb, wqb, Qw, Kw, Vtw);

  attn_kernel<<<dim3(1536), 128, 0, stream>>>(Qw, Kw, Vtw, Ow);

  out_gemm<<<dim3(MTOK / 64, DMODEL / BN), 256, 0, stream>>>(Ow, wob, (float*)d_out);
}

// Round 8
// 198.711 us; speedup vs baseline: 1.0838x; 1.0838x over previous
//
#include <hip/hip_runtime.h>
#include <stdint.h>

#define DMODEL 768
#define NHEADS 12
#define DK 64
#define BATCH 4
#define SEQ 2048
#define MTOK (BATCH*SEQ)   // 8192 tokens

typedef float f32x4 __attribute__((ext_vector_type(4)));
typedef float f32x16 __attribute__((ext_vector_type(16)));
typedef short bf16x8 __attribute__((ext_vector_type(8)));
typedef unsigned short u16;
typedef unsigned int u32;

#define LOG2E 1.4426950408889634f

__device__ __forceinline__ u16 f2bf(float f) {
  uint32_t u = __float_as_uint(f);
  u += 0x7FFFu + ((u >> 16) & 1u);   // RNE
  return (u16)(u >> 16);
}

// async global->LDS, 16B per lane; LDS dest is wave-uniform base + lane*16
#define GLDS16(g, l) __builtin_amdgcn_global_load_lds( \
    (const __attribute__((address_space(1))) unsigned int*)(g), \
    (__attribute__((address_space(3))) unsigned int*)(l), 16, 0, 0)

// ---------------- fused fp32 -> bf16 convert (x + 4 weights, one launch) ----------------
__global__ void cvt_all(const float* __restrict__ x,
                        const float* __restrict__ wq, const float* __restrict__ wk,
                        const float* __restrict__ wv, const float* __restrict__ wo,
                        u16* __restrict__ xb, u16* __restrict__ wb) {
  const int NX = MTOK * DMODEL / 4;     // 1,572,864
  const int NW = DMODEL * DMODEL / 4;   // 147,456
  int i = blockIdx.x * blockDim.x + threadIdx.x;
  const float* src; u16* dst; int idx;
  if (i < NX) {
    src = x; dst = xb; idx = i;
  } else {
    const int j = i - NX;
    const int w = j / NW;               // 0..3 (constant divisor -> magic mul)
    idx = j - w * NW;
    src = (w == 0) ? wq : (w == 1) ? wk : (w == 2) ? wv : wo;
    dst = wb + (size_t)w * DMODEL * DMODEL;
  }
  float4 v = reinterpret_cast<const float4*>(src)[idx];
  ushort4 o;
  o.x = f2bf(v.x); o.y = f2bf(v.y); o.z = f2bf(v.z); o.w = f2bf(v.w);
  reinterpret_cast<ushort4*>(dst)[idx] = o;
}

// ---------------- GEMM main loop: 128x128 tile, 8 waves (R3-verified) ----------------
#define BM 128
#define BN 128
#define BK 32

__device__ __forceinline__ void gemm_loop(const u16* __restrict__ A, const u16* __restrict__ W,
                                          int bm, int bn, int t, u16* As, u16* Ws,
                                          f32x4 (&acc)[2][4]) {
  const int lane = t & 63;
  const int wave = t >> 6;              // 0..7
  const int r16 = lane & 15, g = lane >> 4;
  const int wr = (wave >> 1) * 32;
  const int wc = (wave & 1) * 64;
  // 512 chunks of 16B per matrix; thread t handles chunk t
  // chunk c: row = c>>2, LDS slot = c*16B, source col-chunk = (c&3)^((c>>3)&3)
  const int crow = t >> 2;
  const int cchunk = (t & 3) ^ ((t >> 3) & 3);
  const size_t aoff = (size_t)(bm + crow) * DMODEL + cchunk * 8;
  const size_t woff = (size_t)(bn + crow) * DMODEL + cchunk * 8;

  GLDS16(A + aoff, As + t * 8);
  GLDS16(W + woff, Ws + t * 8);
  __syncthreads();

  const int NK = DMODEL / BK;   // 24
  for (int kt = 0; kt < NK; ++kt) {
    const int cur = kt & 1;
    if (kt + 1 < NK) {
      GLDS16(A + aoff + (size_t)(kt + 1) * BK, As + (cur ^ 1) * 4096 + t * 8);
      GLDS16(W + woff + (size_t)(kt + 1) * BK, Ws + (cur ^ 1) * 4096 + t * 8);
    }
    bf16x8 af[2], bfr[4];
#pragma unroll
    for (int m = 0; m < 2; ++m) {
      const int row = wr + m * 16 + r16;
      af[m] = *reinterpret_cast<const bf16x8*>(&As[cur * 4096 + row * 32 + ((g ^ ((row >> 1) & 3)) * 8)]);
    }
#pragma unroll
    for (int n = 0; n < 4; ++n) {
      const int row = wc + n * 16 + r16;
      bfr[n] = *reinterpret_cast<const bf16x8*>(&Ws[cur * 4096 + row * 32 + ((g ^ ((row >> 1) & 3)) * 8)]);
    }
#pragma unroll
    for (int m = 0; m < 2; ++m)
#pragma unroll
      for (int n = 0; n < 4; ++n)
        acc[m][n] = __builtin_amdgcn_mfma_f32_16x16x32_bf16(af[m], bfr[n], acc[m][n], 0, 0, 0);
    __syncthreads();
  }
}

// Fused QKV projection: z=0 Q (pre-scaled by 0.125*log2e), z=1 K, z=2 V^T
__launch_bounds__(512)
__global__ void qkv_gemm(const u16* __restrict__ A, const u16* __restrict__ wAll,
                         u16* __restrict__ Qw, u16* __restrict__ Kw, u16* __restrict__ Vtw) {
  __shared__ __align__(16) u16 As[2 * BM * BK];
  __shared__ __align__(16) u16 Ws[2 * BN * BK];
  const int t = threadIdx.x;
  const int lane = t & 63, wave = t >> 6;
  const int r16 = lane & 15, g = lane >> 4;
  const int bm = blockIdx.x * BM, bn = blockIdx.y * BN;
  const int z = blockIdx.z;
  const u16* W = wAll + (size_t)z * DMODEL * DMODEL;
  const int wr = (wave >> 1) * 32, wc = (wave & 1) * 64;

  f32x4 acc[2][4] = {};
  gemm_loop(A, W, bm, bn, t, As, Ws, acc);

  if (z <= 1) {
    u16* Qo = (z == 0) ? Qw : Kw;
    const float scl = (z == 0) ? (0.125f * LOG2E) : 1.0f;  // base-2 softmax domain
#pragma unroll
    for (int m = 0; m < 2; ++m) {
      const int gi0 = bm + wr + m * 16 + g * 4;
#pragma unroll
      for (int n = 0; n < 4; ++n) {
        const int gj = bn + wc + n * 16 + r16;
        const int h = gj >> 6, dc = gj & 63;
#pragma unroll
        for (int r = 0; r < 4; ++r) {
          const int gi = gi0 + r;
          const int b_ = gi >> 11, s = gi & 2047;
          Qo[((size_t)((b_ * NHEADS + h) * SEQ + s) << 6) + dc] = f2bf(acc[m][n][r] * scl);
        }
      }
    }
  } else {
    // V^T: Vo[b][h][dc][s], 4 consecutive s per lane -> packed ushort4 store
#pragma unroll
    for (int m = 0; m < 2; ++m) {
      const int gi0 = bm + wr + m * 16 + g * 4;
      const int b_ = gi0 >> 11, s0 = gi0 & 2047;
#pragma unroll
      for (int n = 0; n < 4; ++n) {
        const int gj = bn + wc + n * 16 + r16;
        const int h = gj >> 6, dc = gj & 63;
        ushort4 pk;
        pk.x = f2bf(acc[m][n][0]); pk.y = f2bf(acc[m][n][1]);
        pk.z = f2bf(acc[m][n][2]); pk.w = f2bf(acc[m][n][3]);
        *reinterpret_cast<ushort4*>(Vtw + ((size_t)((b_ * NHEADS + h) * DK + dc) * SEQ + s0)) = pk;
      }
    }
  }
}

// Output projection: fp32 out row-major [M][N]
__launch_bounds__(512)
__global__ void out_gemm(const u16* __restrict__ A, const u16* __restrict__ W,
                         float* __restrict__ C) {
  __shared__ __align__(16) u16 As[2 * BM * BK];
  __shared__ __align__(16) u16 Ws[2 * BN * BK];
  const int t = threadIdx.x;
  const int lane = t & 63, wave = t >> 6;
  const int r16 = lane & 15, g = lane >> 4;
  const int bm = blockIdx.x * BM, bn = blockIdx.y * BN;
  const int wr = (wave >> 1) * 32, wc = (wave & 1) * 64;

  f32x4 acc[2][4] = {};
  gemm_loop(A, W, bm, bn, t, As, Ws, acc);

#pragma unroll
  for (int m = 0; m < 2; ++m) {
    const int gi0 = bm + wr + m * 16 + g * 4;
#pragma unroll
    for (int n = 0; n < 4; ++n) {
      const int gj = bn + wc + n * 16 + r16;
#pragma unroll
      for (int r = 0; r < 4; ++r)
        C[(size_t)(gi0 + r) * DMODEL + gj] = acc[m][n][r];
    }
  }
}

// ---- P fragment assembly: 8 own f32 P-values -> bf16x8 PV B-operand frag ----
__device__ __forceinline__ bf16x8 mk_pa(int hi, float p0, float p1, float p2, float p3,
                                        float p4, float p5, float p6, float p7) {
  u32 w01, w23, w45, w67;
  asm("v_cvt_pk_bf16_f32 %0, %1, %2" : "=v"(w01) : "v"(p0), "v"(p1));
  asm("v_cvt_pk_bf16_f32 %0, %1, %2" : "=v"(w23) : "v"(p2), "v"(p3));
  asm("v_cvt_pk_bf16_f32 %0, %1, %2" : "=v"(w45) : "v"(p4), "v"(p5));
  asm("v_cvt_pk_bf16_f32 %0, %1, %2" : "=v"(w67) : "v"(p6), "v"(p7));
  const u32 pw01 = (u32)__shfl_xor((int)w01, 32);
  const u32 pw23 = (u32)__shfl_xor((int)w23, 32);
  const u32 pw45 = (u32)__shfl_xor((int)w45, 32);
  const u32 pw67 = (u32)__shfl_xor((int)w67, 32);
  union { u32 w[4]; bf16x8 v; } u;
  u.w[0] = hi ? pw45 : w01;
  u.w[1] = hi ? pw67 : w23;
  u.w[2] = hi ? w45  : pw01;
  u.w[3] = hi ? w67  : pw23;
  return u.v;
}

__device__ __forceinline__ float max3f(float a, float b, float c) {
  return fmaxf(fmaxf(a, b), c);   // clang fuses to v_max3_f32
}

// ---------------- causal flash attention (R6 4-warp body + max3 + defer-max) ----------------
// 4 warps x 32 q-rows = 128 q/block; KV tiles of 64, GLDS dbuf; grid 768 LPT.
__launch_bounds__(256, 2)
__global__ void attn_kernel(const u16* __restrict__ Qg, const u16* __restrict__ Kg,
                            const u16* __restrict__ Vtg, u16* __restrict__ Og) {
  __shared__ __align__(16) u16 Ks[2][64 * 64];
  __shared__ __align__(16) u16 Vs[2][64 * 64];
  const int t = threadIdx.x;
  const int lane = t & 63, warp = t >> 6;
  const int l31 = lane & 31, hi = lane >> 5;
  const int bx = blockIdx.x;            // 0..767
  const int qt = 15 - (bx / 48);        // LPT: heaviest q-blocks first
  const int hb = bx % 48;
  const int h = hb % NHEADS, b = hb / NHEADS;
  const int q0w = qt * 128 + warp * 32;
  const int nt = 2 * qt + 2;            // kv tiles this block needs
  const size_t bh = (size_t)(b * NHEADS + h);
  const u16* Qb = Qg + bh * SEQ * DK;
  const u16* Kb = Kg + bh * SEQ * DK;
  const u16* Vb = Vtg + bh * DK * SEQ;  // [d][s]

  // staging map: LDS byte bb -> tile row bb>>7, source col ((bb&127)^((row&7)<<4))>>1
  int srow[2], scol[2];
#pragma unroll
  for (int j = 0; j < 2; ++j) {
    const int bb = (t + j * 256) * 16;
    srow[j] = bb >> 7;
    scol[j] = ((bb & 127) ^ ((srow[j] & 7) << 4)) >> 1;
  }

  const int q = q0w + l31;              // this lane's q-row
  bf16x8 qf[4];                         // Q pre-scaled by 0.125*log2e in projection
#pragma unroll
  for (int kk = 0; kk < 4; ++kk)
    qf[kk] = *reinterpret_cast<const bf16x8*>(Qb + (size_t)q * DK + kk * 16 + hi * 8);

  f32x16 o0 = {}, o1 = {};              // O^T: d = crow(reg,hi) + 32*{0,1}
  float m = -__builtin_inff(), l = 0.f;
  const int hi4 = hi * 4;
  const int xr = (l31 & 7) << 4;

  // prologue: stage tile 0 into buffer 0
#pragma unroll
  for (int j = 0; j < 2; ++j) {
    GLDS16(Kb + (size_t)srow[j] * DK + scol[j], &Ks[0][0] + (t + j * 256) * 8);
    GLDS16(Vb + (size_t)srow[j] * SEQ + scol[j], &Vs[0][0] + (t + j * 256) * 8);
  }
  __syncthreads();

  for (int i = 0; i < nt; ++i) {
    const int cur = i & 1;
    const int kv0 = i * 64;
    if (i + 1 < nt) {                   // issue next tile early
      const int nkv0 = kv0 + 64;
#pragma unroll
      for (int j = 0; j < 2; ++j) {
        GLDS16(Kb + (size_t)(nkv0 + srow[j]) * DK + scol[j], &Ks[cur ^ 1][0] + (t + j * 256) * 8);
        GLDS16(Vb + (size_t)srow[j] * SEQ + nkv0 + scol[j], &Vs[cur ^ 1][0] + (t + j * 256) * 8);
      }
    }

    if (kv0 <= q0w + 31) {              // warp-uniform active check
      // ---- T = K Q^T (scores already in base-2 domain) ----
      f32x16 t0 = {}, t1 = {};
      const char* Kc = (const char*)Ks[cur];
      __builtin_amdgcn_s_setprio(1);
#pragma unroll
      for (int kk = 0; kk < 4; ++kk) {
        const int cb = kk * 32 + hi * 16;
        bf16x8 a0 = *reinterpret_cast<const bf16x8*>(Kc + ((l31 * 128 + cb) ^ xr));
        bf16x8 a1 = *reinterpret_cast<const bf16x8*>(Kc + (((l31 + 32) * 128 + cb) ^ xr));
        t0 = __builtin_amdgcn_mfma_f32_32x32x16_bf16(a0, qf[kk], t0, 0, 0, 0);
        t1 = __builtin_amdgcn_mfma_f32_32x32x16_bf16(a1, qf[kk], t1, 0, 0, 0);
      }
      __builtin_amdgcn_s_setprio(0);

      // ---- causal mask (diag tile only) ----
      if (kv0 + 63 > q0w) {
        const int qmh = (q - kv0) - hi4;
#pragma unroll
        for (int r = 0; r < 16; ++r) {
          const int kvc = (r & 3) + 8 * (r >> 2);
          if (kvc > qmh)      t0[r] = -__builtin_inff();
          if (kvc + 32 > qmh) t1[r] = -__builtin_inff();
        }
      }

      // ---- row max (max3-fused tree) ----
      float a0_ = max3f(t0[0], t0[1], t0[2]);
      float a1_ = max3f(t0[3], t0[4], t0[5]);
      float a2_ = max3f(t0[6], t0[7], t0[8]);
      float a3_ = max3f(t0[9], t0[10], t0[11]);
      float a4_ = max3f(t0[12], t0[13], t0[14]);
      float a5_ = max3f(t0[15], t1[0], t1[1]);
      float a6_ = max3f(t1[2], t1[3], t1[4]);
      float a7_ = max3f(t1[5], t1[6], t1[7]);
      float a8_ = max3f(t1[8], t1[9], t1[10]);
      float a9_ = max3f(t1[11], t1[12], t1[13]);
      float aa_ = fmaxf(t1[14], t1[15]);
      float b0_ = max3f(a0_, a1_, a2_);
      float b1_ = max3f(a3_, a4_, a5_);
      float b2_ = max3f(a6_, a7_, a8_);
      float b3_ = max3f(a9_, aa_, b0_);
      float pm = max3f(b1_, b2_, b3_);
      pm = fmaxf(pm, __shfl_xor(pm, 32));

      // ---- defer-max (T13, THR=8 in base-2 domain: P <= 2^8) ----
      if (__any(pm > m + 8.f)) {
        const float mnew = fmaxf(m, pm);
        const float corr = __builtin_amdgcn_exp2f(m - mnew);
        l *= corr;
        o0 = o0 * corr;
        o1 = o1 * corr;
        m = mnew;
      }

      // ---- exp2 + row sum ----
#pragma unroll
      for (int r = 0; r < 16; ++r) { t0[r] = __builtin_amdgcn_exp2f(t0[r] - m); }
#pragma unroll
      for (int r = 0; r < 16; ++r) { t1[r] = __builtin_amdgcn_exp2f(t1[r] - m); }
      float s0 = 0.f, s1 = 0.f, s2 = 0.f, s3 = 0.f;
#pragma unroll
      for (int r = 0; r < 4; ++r) {
        s0 += t0[r]; s1 += t0[4 + r]; s2 += t0[8 + r]; s3 += t0[12 + r];
        s0 += t1[r]; s1 += t1[4 + r]; s2 += t1[8 + r]; s3 += t1[12 + r];
      }
      float s = (s0 + s1) + (s2 + s3);
      l += s + __shfl_xor(s, 32);

      // ---- P -> bf16 PV fragments (in-register) ----
      bf16x8 pa0 = mk_pa(hi, t0[0], t0[1], t0[2], t0[3], t0[4], t0[5], t0[6], t0[7]);
      bf16x8 pa1 = mk_pa(hi, t0[8], t0[9], t0[10], t0[11], t0[12], t0[13], t0[14], t0[15]);
      bf16x8 pa2 = mk_pa(hi, t1[0], t1[1], t1[2], t1[3], t1[4], t1[5], t1[6], t1[7]);
      bf16x8 pa3 = mk_pa(hi, t1[8], t1[9], t1[10], t1[11], t1[12], t1[13], t1[14], t1[15]);

      // ---- O^T += V^T P^T ----
      const char* Vc = (const char*)Vs[cur];
      __builtin_amdgcn_s_setprio(1);
#pragma unroll
      for (int ks = 0; ks < 4; ++ks) {
        const int cb = ks * 32 + hi * 16;
        bf16x8 v0 = *reinterpret_cast<const bf16x8*>(Vc + ((l31 * 128 + cb) ^ xr));
        bf16x8 v1 = *reinterpret_cast<const bf16x8*>(Vc + (((l31 + 32) * 128 + cb) ^ xr));
        const bf16x8 pk = (ks == 0) ? pa0 : (ks == 1) ? pa1 : (ks == 2) ? pa2 : pa3;
        o0 = __builtin_amdgcn_mfma_f32_32x32x16_bf16(v0, pk, o0, 0, 0, 0);
        o1 = __builtin_amdgcn_mfma_f32_32x32x16_bf16(v1, pk, o1, 0, 0, 0);
      }
      __builtin_amdgcn_s_setprio(0);
    }
    __syncthreads();                    // drains GLDS (vmcnt) + publishes buf^1
  }

  // ---- epilogue: O^T/l -> Og[tok][DMODEL] ----
  const float rinv = 1.0f / l;
  u16* orow = Og + (size_t)(b * SEQ + q) * DMODEL + h * 64;
#pragma unroll
  for (int j = 0; j < 4; ++j) {
    ushort4 pk;
    pk.x = f2bf(o0[4 * j + 0] * rinv); pk.y = f2bf(o0[4 * j + 1] * rinv);
    pk.z = f2bf(o0[4 * j + 2] * rinv); pk.w = f2bf(o0[4 * j + 3] * rinv);
    *reinterpret_cast<ushort4*>(orow + 8 * j + hi4) = pk;
  }
#pragma unroll
  for (int j = 0; j < 4; ++j) {
    ushort4 pk;
    pk.x = f2bf(o1[4 * j + 0] * rinv); pk.y = f2bf(o1[4 * j + 1] * rinv);
    pk.z = f2bf(o1[4 * j + 2] * rinv); pk.w = f2bf(o1[4 * j + 3] * rinv);
    *reinterpret_cast<ushort4*>(orow + 32 + 8 * j + hi4) = pk;
  }
}

// ---------------- launch ----------------
extern "C" void kernel_launch(void* const* d_in, const int* in_sizes, int n_in,
                              void* d_out, int out_size, void* d_ws, size_t ws_size,
                              hipStream_t stream) {
  const float* x  = (const float*)d_in[0];
  const float* wq = (const float*)d_in[1];
  const float* wk = (const float*)d_in[2];
  const float* wv = (const float*)d_in[3];
  const float* wo = (const float*)d_in[4];

  const size_t SZ_TOK = (size_t)MTOK * DMODEL * 2;
  const size_t SZ_W   = (size_t)DMODEL * DMODEL * 2;
  char* ws = (char*)d_ws;
  size_t off = 0;
  u16* xb  = (u16*)(ws + off); off += SZ_TOK;
  u16* wqb = (u16*)(ws + off); off += 4 * SZ_W;   // wq,wk,wv,wo contiguous
  u16* Qw  = (u16*)(ws + off); off += SZ_TOK;
  u16* Kw  = (u16*)(ws + off); off += SZ_TOK;
  u16* Vtw = (u16*)(ws + off); off += SZ_TOK;     // [B,H,DK,S]
  u16* Ow  = (u16*)(ws + off); off += SZ_TOK;
  if (ws_size < off) return;
  u16* wob = wqb + 3 * (size_t)DMODEL * DMODEL;

  const int NX = MTOK * DMODEL / 4;
  const int NW = DMODEL * DMODEL / 4;
  cvt_all<<<(NX + 4 * NW) / 256, 256, 0, stream>>>(x, wq, wk, wv, wo, xb, wqb);

  qkv_gemm<<<dim3(MTOK / BM, DMODEL / BN, 3), 512, 0, stream>>>(xb, wqb, Qw, Kw, Vtw);

  attn_kernel<<<dim3(768), 256, 0, stream>>>(Qw, Kw, Vtw, Ow);

  out_gemm<<<dim3(MTOK / BM, DMODEL / BN), 512, 0, stream>>>(Ow, wob, (float*)d_out);
}